// Round 1
// baseline (145.206 us; speedup 1.0000x reference)
//
#include <hip/hip_runtime.h>

#define EPS_BN 1e-5f

// ---------------------------------------------------------------------------
// Kernel A: 1x1 conv (256->64) + BN + SiLU.  Output T in NHWC: T[(b,h,w),oc]
// grid (ochalf=2, h=48, b=2), block 384
// ---------------------------------------------------------------------------
__global__ __launch_bounds__(384) void comp_kernel(
    const float* __restrict__ X, const float* __restrict__ Wc,
    const float* __restrict__ g1, const float* __restrict__ b1,
    const float* __restrict__ m1, const float* __restrict__ v1,
    float* __restrict__ T)
{
    const int ochalf = blockIdx.x;
    const int h = blockIdx.y;
    const int b = blockIdx.z;
    __shared__ float xrow[256*52];   // [ci][w], stride 52 (f4-aligned, bank-safe)
    __shared__ float wc[32*260];     // [ocl][ci], stride 260 (f4-aligned)
    const int tid = threadIdx.x;

    for (int idx = tid; idx < 256*48; idx += 384) {
        int ci = idx / 48;
        int w  = idx - ci*48;
        xrow[ci*52 + w] = X[(b*256 + ci)*2304 + h*48 + w];
    }
    for (int idx = tid; idx < 32*256; idx += 384) {
        int ocl = idx >> 8;
        int ci  = idx & 255;
        wc[ocl*260 + ci] = Wc[(ochalf*32 + ocl)*256 + ci];
    }
    __syncthreads();

    const int ocl = tid & 31;
    const int wg  = tid >> 5;      // 0..11
    const int w0  = wg*4;
    float a0=0.f, a1=0.f, a2=0.f, a3=0.f;
    for (int c4 = 0; c4 < 64; ++c4) {
        const float4 wv = *(const float4*)&wc[ocl*260 + c4*4];
        const float4 x0 = *(const float4*)&xrow[(c4*4+0)*52 + w0];
        const float4 x1 = *(const float4*)&xrow[(c4*4+1)*52 + w0];
        const float4 x2 = *(const float4*)&xrow[(c4*4+2)*52 + w0];
        const float4 x3 = *(const float4*)&xrow[(c4*4+3)*52 + w0];
        a0 = fmaf(wv.x,x0.x,fmaf(wv.y,x1.x,fmaf(wv.z,x2.x,fmaf(wv.w,x3.x,a0))));
        a1 = fmaf(wv.x,x0.y,fmaf(wv.y,x1.y,fmaf(wv.z,x2.y,fmaf(wv.w,x3.y,a1))));
        a2 = fmaf(wv.x,x0.z,fmaf(wv.y,x1.z,fmaf(wv.z,x2.z,fmaf(wv.w,x3.z,a2))));
        a3 = fmaf(wv.x,x0.w,fmaf(wv.y,x1.w,fmaf(wv.z,x2.w,fmaf(wv.w,x3.w,a3))));
    }
    const int oc = ochalf*32 + ocl;
    const float sc = g1[oc] * rsqrtf(v1[oc] + EPS_BN);
    const float sh = b1[oc] - m1[oc]*sc;
    float vals[4] = {a0, a1, a2, a3};
    #pragma unroll
    for (int wi = 0; wi < 4; ++wi) {
        float v = fmaf(vals[wi], sc, sh);
        float t = v / (1.f + __expf(-v));          // SiLU
        T[((b*48 + h)*48 + (w0 + wi))*64 + oc] = t;
    }
}

// ---------------------------------------------------------------------------
// Kernel B: 3x3 conv (64->100) + BN + per-(s,pixel) softmax over k=0..24.
// Block handles the 25 channels {4k+s} of one (b,h) row -> softmax is local.
// Stores Wl[pix][s][28] (k-padded to 28 for f4 reads in kernel C).
// grid (s=4, h=48, b=2), block 256
// ---------------------------------------------------------------------------
__global__ __launch_bounds__(256) void enc_kernel(
    const float* __restrict__ T, const float* __restrict__ We,
    const float* __restrict__ g2, const float* __restrict__ b2,
    const float* __restrict__ m2, const float* __restrict__ v2,
    float* __restrict__ Wl)
{
    const int s = blockIdx.x;
    const int h = blockIdx.y;
    const int b = blockIdx.z;
    __shared__ float tl[9600];    // [(ci>>2)][r:3][col:50][ci&3]  (ci interleave-4)
    __shared__ float wl[14400];   // [k:25][kk:9][ci:64]
    __shared__ float ebuf[1200];  // [w:48][k:25]
    const int tid = threadIdx.x;

    for (int idx = tid; idx < 9600; idx += 256) {
        int ci  = idx & 63;
        int tmp = idx >> 6;
        int r   = tmp / 50;
        int col = tmp - r*50;
        int hh = h - 1 + r;
        int w  = col - 1;
        float val = 0.f;
        if (hh >= 0 && hh < 48 && (unsigned)w < 48u)
            val = T[((b*48 + hh)*48 + w)*64 + ci];
        tl[(((ci>>2)*3 + r)*50 + col)*4 + (ci&3)] = val;
    }
    for (int idx = tid; idx < 14400; idx += 256) {
        int k   = idx / 576;
        int rem = idx - k*576;
        int ci  = rem / 9;
        int kk  = rem - ci*9;
        wl[k*576 + kk*64 + ci] = We[(4*k + s)*576 + rem];
    }
    __syncthreads();

    if (tid < 240) {
        const int w   = tid % 48;
        const int chg = tid / 48;   // 5 k's per thread
        float acc[5] = {0.f,0.f,0.f,0.f,0.f};
        for (int kk = 0; kk < 9; ++kk) {
            const int ky = kk/3, kx = kk - ky*3;
            const float* tb = &tl[(ky*50 + (w + kx))*4];
            const float* wb = &wl[(chg*5*9 + kk)*64];
            for (int c4 = 0; c4 < 16; ++c4) {
                const float4 tv = *(const float4*)&tb[c4*600];
                #pragma unroll
                for (int i = 0; i < 5; ++i) {
                    const float4 wv = *(const float4*)&wb[i*576 + c4*4];
                    acc[i] = fmaf(tv.x,wv.x,fmaf(tv.y,wv.y,fmaf(tv.z,wv.z,fmaf(tv.w,wv.w,acc[i]))));
                }
            }
        }
        #pragma unroll
        for (int i = 0; i < 5; ++i) {
            const int k  = chg*5 + i;
            const int ch = 4*k + s;
            const float sc = g2[ch] * rsqrtf(v2[ch] + EPS_BN);
            const float sh = b2[ch] - m2[ch]*sc;
            ebuf[w*25 + k] = fmaf(acc[i], sc, sh);
        }
    }
    __syncthreads();

    if (tid < 48) {
        float ev[25];
        float mx = -1e30f;
        #pragma unroll
        for (int k = 0; k < 25; ++k) { ev[k] = ebuf[tid*25 + k]; mx = fmaxf(mx, ev[k]); }
        float sum = 0.f;
        #pragma unroll
        for (int k = 0; k < 25; ++k) { ev[k] = __expf(ev[k] - mx); sum += ev[k]; }
        const float rs = 1.f / sum;
        const int base = ((b*48 + h)*48 + tid)*112 + s*28;
        #pragma unroll
        for (int k = 0; k < 25; ++k) Wl[base + k] = ev[k]*rs;
    }
}

// ---------------------------------------------------------------------------
// Kernel C: reassembly. out[b,c,2h+sy,2w+sx] = sum_{dy,dx in [-2,2]}
//   Wl[(h,w)][s][ (dy+2)*5+(dx+2) ] * X[b,c,h+dy,w+dx]   (zero-padded X)
// grid (cg=4 of 64 ch, h=48, b=2), block 256
// ---------------------------------------------------------------------------
__global__ __launch_bounds__(256) void carafe_kernel(
    const float* __restrict__ X, const float* __restrict__ Wl,
    float* __restrict__ out)
{
    const int cg = blockIdx.x;
    const int h = blockIdx.y;
    const int b = blockIdx.z;
    __shared__ float xl[16960];   // [(ci>>2)][r:5][cp:53][ci&3]  (ci interleave-4)
    __shared__ float wrow[5376];  // [w:48][s:4][28]
    const int tid = threadIdx.x;

    for (int idx = tid; idx < 64*265; idx += 256) {
        int ci  = idx / 265;
        int rem = idx - ci*265;
        int r   = rem / 53;
        int cp  = rem - r*53;
        int hh = h - 2 + r;
        int w  = cp - 2;
        float val = 0.f;
        if (hh >= 0 && hh < 48 && (unsigned)w < 48u)
            val = X[(b*256 + cg*64 + ci)*2304 + hh*48 + w];
        xl[(((ci>>2)*5 + r)*53 + cp)*4 + (ci&3)] = val;
    }
    for (int idx = tid; idx < 5376; idx += 256)
        wrow[idx] = Wl[((b*48 + h)*48)*112 + idx];
    __syncthreads();

    const int c4g = tid & 15;   // 4 channels: cg*64 + c4g*4 + {0..3}
    const int wg  = tid >> 4;   // 0..15, 3 w's each
    for (int wi = 0; wi < 3; ++wi) {
        const int w = wg*3 + wi;
        float4 xv[25];
        #pragma unroll
        for (int r = 0; r < 5; ++r)
            #pragma unroll
            for (int dx = 0; dx < 5; ++dx)
                xv[r*5 + dx] = *(const float4*)&xl[((c4g*5 + r)*53 + (w + dx))*4];
        const float* wb = &wrow[w*112];
        #pragma unroll
        for (int s = 0; s < 4; ++s) {
            float ax=0.f, ay=0.f, az=0.f, aw=0.f;
            #pragma unroll
            for (int k4 = 0; k4 < 6; ++k4) {
                const float4 wv = *(const float4*)&wb[s*28 + k4*4];
                const float4 p0 = xv[k4*4+0], p1 = xv[k4*4+1], p2 = xv[k4*4+2], p3 = xv[k4*4+3];
                ax = fmaf(wv.x,p0.x,fmaf(wv.y,p1.x,fmaf(wv.z,p2.x,fmaf(wv.w,p3.x,ax))));
                ay = fmaf(wv.x,p0.y,fmaf(wv.y,p1.y,fmaf(wv.z,p2.y,fmaf(wv.w,p3.y,ay))));
                az = fmaf(wv.x,p0.z,fmaf(wv.y,p1.z,fmaf(wv.z,p2.z,fmaf(wv.w,p3.z,az))));
                aw = fmaf(wv.x,p0.w,fmaf(wv.y,p1.w,fmaf(wv.z,p2.w,fmaf(wv.w,p3.w,aw))));
            }
            const float wk = wb[s*28 + 24];
            const float4 pl = xv[24];
            ax = fmaf(wk,pl.x,ax); ay = fmaf(wk,pl.y,ay);
            az = fmaf(wk,pl.z,az); aw = fmaf(wk,pl.w,aw);
            const int y = 2*h + (s>>1);
            const int x = 2*w + (s&1);
            float* ob = &out[((size_t)(b*256 + cg*64 + c4g*4)*96 + y)*96 + x];
            ob[0]     = ax;
            ob[9216]  = ay;
            ob[18432] = az;
            ob[27648] = aw;
        }
    }
}

extern "C" void kernel_launch(void* const* d_in, const int* in_sizes, int n_in,
                              void* d_out, int out_size, void* d_ws, size_t ws_size,
                              hipStream_t stream)
{
    (void)in_sizes; (void)n_in; (void)out_size; (void)ws_size;
    const float* X      = (const float*)d_in[0];
    const float* w_comp = (const float*)d_in[1];
    const float* g1     = (const float*)d_in[2];
    const float* b1     = (const float*)d_in[3];
    const float* m1     = (const float*)d_in[4];
    const float* v1     = (const float*)d_in[5];
    const float* w_enc  = (const float*)d_in[6];
    const float* g2     = (const float*)d_in[7];
    const float* b2     = (const float*)d_in[8];
    const float* m2     = (const float*)d_in[9];
    const float* v2     = (const float*)d_in[10];
    float* out = (float*)d_out;

    float* T  = (float*)d_ws;                 // 2*48*48*64   = 294912 floats
    float* Wl = T + 294912;                   // 2*48*48*112  = 516096 floats

    dim3 gA(2, 48, 2);
    comp_kernel<<<gA, 384, 0, stream>>>(X, w_comp, g1, b1, m1, v1, T);
    dim3 gB(4, 48, 2);
    enc_kernel<<<gB, 256, 0, stream>>>(T, w_enc, g2, b2, m2, v2, Wl);
    dim3 gC(4, 48, 2);
    carafe_kernel<<<gC, 256, 0, stream>>>(X, Wl, out);
}

// Round 2
// 99.570 us; speedup vs baseline: 1.4583x; 1.4583x over previous
//
#include <hip/hip_runtime.h>

#define EPS_BN 1e-5f

typedef __attribute__((ext_vector_type(8))) short short8v;
typedef __attribute__((ext_vector_type(4))) float f32x4;

__device__ inline unsigned short f2bf(float f) {
    union { float f; unsigned u; } v; v.f = f;
    unsigned r = v.u + 0x7fffu + ((v.u >> 16) & 1u);
    return (unsigned short)(r >> 16);
}

// ---------------------------------------------------------------------------
// Kernel P: zero t_pad, build Web[ch 128][kk*64+ci] bf16 from w_enc[ch][ci][kk]
// ---------------------------------------------------------------------------
__global__ __launch_bounds__(256) void prep_kernel(
    const float* __restrict__ w_enc, unsigned int* __restrict__ tpad_u32,
    unsigned short* __restrict__ Web)
{
    const int tid = blockIdx.x * 256 + threadIdx.x;
    const int nthr = gridDim.x * 256;
    for (int i = tid; i < 160000; i += nthr)       // 2*50*50*64 bf16 = 160000 u32
        tpad_u32[i] = 0u;
    for (int i = tid; i < 128 * 576; i += nthr) {
        int ch = i / 576;
        int r  = i - ch * 576;
        int kk = r >> 6;
        int ci = r & 63;
        float v = (ch < 100) ? w_enc[ch * 576 + ci * 9 + kk] : 0.f;
        Web[i] = f2bf(v);
    }
}

// ---------------------------------------------------------------------------
// Kernel A: 1x1 conv (256->64) + BN + SiLU -> t_pad bf16 [b][50][50][64]
// grid (ochalf=2, h=48, b=2), block 384
// ---------------------------------------------------------------------------
__global__ __launch_bounds__(384) void comp_kernel(
    const float* __restrict__ X, const float* __restrict__ Wc,
    const float* __restrict__ g1, const float* __restrict__ b1,
    const float* __restrict__ m1, const float* __restrict__ v1,
    unsigned short* __restrict__ tpad)
{
    const int ochalf = blockIdx.x;
    const int h = blockIdx.y;
    const int b = blockIdx.z;
    __shared__ float xrow[256*52];
    __shared__ float wc[32*260];
    const int tid = threadIdx.x;

    for (int idx = tid; idx < 256*48; idx += 384) {
        int ci = idx / 48;
        int w  = idx - ci*48;
        xrow[ci*52 + w] = X[(b*256 + ci)*2304 + h*48 + w];
    }
    for (int idx = tid; idx < 32*256; idx += 384) {
        int ocl = idx >> 8;
        int ci  = idx & 255;
        wc[ocl*260 + ci] = Wc[(ochalf*32 + ocl)*256 + ci];
    }
    __syncthreads();

    const int ocl = tid & 31;
    const int wg  = tid >> 5;
    const int w0  = wg*4;
    float a0=0.f, a1=0.f, a2=0.f, a3=0.f;
    for (int c4 = 0; c4 < 64; ++c4) {
        const float4 wv = *(const float4*)&wc[ocl*260 + c4*4];
        const float4 x0 = *(const float4*)&xrow[(c4*4+0)*52 + w0];
        const float4 x1 = *(const float4*)&xrow[(c4*4+1)*52 + w0];
        const float4 x2 = *(const float4*)&xrow[(c4*4+2)*52 + w0];
        const float4 x3 = *(const float4*)&xrow[(c4*4+3)*52 + w0];
        a0 = fmaf(wv.x,x0.x,fmaf(wv.y,x1.x,fmaf(wv.z,x2.x,fmaf(wv.w,x3.x,a0))));
        a1 = fmaf(wv.x,x0.y,fmaf(wv.y,x1.y,fmaf(wv.z,x2.y,fmaf(wv.w,x3.y,a1))));
        a2 = fmaf(wv.x,x0.z,fmaf(wv.y,x1.z,fmaf(wv.z,x2.z,fmaf(wv.w,x3.z,a2))));
        a3 = fmaf(wv.x,x0.w,fmaf(wv.y,x1.w,fmaf(wv.z,x2.w,fmaf(wv.w,x3.w,a3))));
    }
    const int oc = ochalf*32 + ocl;
    const float sc = g1[oc] * rsqrtf(v1[oc] + EPS_BN);
    const float sh = b1[oc] - m1[oc]*sc;
    float vals[4] = {a0, a1, a2, a3};
    #pragma unroll
    for (int wi = 0; wi < 4; ++wi) {
        float v = fmaf(vals[wi], sc, sh);
        float t = v / (1.f + __expf(-v));          // SiLU
        tpad[((b*50 + (h+1))*50 + (w0 + wi + 1))*64 + oc] = f2bf(t);
    }
}

// ---------------------------------------------------------------------------
// Kernel B1: 3x3 conv (64->100, padded to 112) via MFMA bf16, BN fused.
// e[px 4608][112] fp32.  grid (wseg=3, h=48, b=2), block 256 (4 waves).
// Wave w computes n-tiles {2w, 2w+1} (ch 32w..32w+31); m-tile = 16 px.
// K = 576 = 9 kk * 64 ci, 18 MFMA k-steps of 32.
// ---------------------------------------------------------------------------
__global__ __launch_bounds__(256) void enc_mfma(
    const unsigned short* __restrict__ tpad, const unsigned short* __restrict__ Web,
    const float* __restrict__ g2, const float* __restrict__ b2,
    const float* __restrict__ m2, const float* __restrict__ v2,
    float* __restrict__ e)
{
    const int wseg = blockIdx.x;
    const int h = blockIdx.y;
    const int b = blockIdx.z;
    const int tid  = threadIdx.x;
    const int wave = tid >> 6;
    const int l    = tid & 63;
    const int lr   = l & 15;      // A-row (px) / B-col (ch) within tile
    const int lk   = l >> 4;      // k-group
    const int w0   = wseg * 16;
    const int nt0  = wave * 2, nt1 = wave * 2 + 1;

    f32x4 acc0 = {0.f,0.f,0.f,0.f};
    f32x4 acc1 = {0.f,0.f,0.f,0.f};

    const unsigned short* tb = tpad + (b*50 + h)*50*64;   // padded row h-1 base
    const unsigned short* wb0 = Web + (nt0*16 + lr)*576;
    const unsigned short* wb1 = Web + (nt1*16 + lr)*576;

    #pragma unroll 6
    for (int s = 0; s < 18; ++s) {
        const int kk = s >> 1;
        const int ky = (kk * 11) >> 5;        // kk/3 for kk in [0,9)
        const int kx = kk - ky * 3;
        const int cio = ((s & 1) << 5) + lk * 8;
        const short8v a  = *(const short8v*)(tb + (ky*50 + w0 + kx + lr)*64 + cio);
        const short8v f0 = *(const short8v*)(wb0 + kk*64 + cio);
        const short8v f1 = *(const short8v*)(wb1 + kk*64 + cio);
        acc0 = __builtin_amdgcn_mfma_f32_16x16x32_bf16(a, f0, acc0, 0, 0, 0);
        acc1 = __builtin_amdgcn_mfma_f32_16x16x32_bf16(a, f1, acc1, 0, 0, 0);
    }

    // Epilogue: BN, store e.  D: col(ch-in-tile)=l&15, row(px-in-tile)=(l>>4)*4+r
    float* erow = e + ((b*48 + h)*48 + w0 + lk*4)*112;
    #pragma unroll
    for (int t = 0; t < 2; ++t) {
        const int nt = t ? nt1 : nt0;
        if (nt >= 7) continue;
        const int ch = nt*16 + lr;
        float sc = 0.f, sh = 0.f;
        if (ch < 100) {
            sc = g2[ch] * rsqrtf(v2[ch] + EPS_BN);
            sh = b2[ch] - m2[ch]*sc;
        }
        const f32x4 acc = t ? acc1 : acc0;
        #pragma unroll
        for (int r = 0; r < 4; ++r)
            erow[r*112 + ch] = fmaf(acc[r], sc, sh);
    }
}

// ---------------------------------------------------------------------------
// Kernel B2: per-(px,s) softmax over k=0..24.  e[px][4k+s] -> Wl[px][s*28+k]
// grid 72 blocks * 256 threads = 18432 = 4608 px * 4 s
// ---------------------------------------------------------------------------
__global__ __launch_bounds__(256) void softmax_kernel(
    const float* __restrict__ e, float* __restrict__ Wl)
{
    const int g = blockIdx.x * 256 + threadIdx.x;
    const int px = g >> 2;
    const int s  = g & 3;
    const float* ep = e + px*112 + s;
    float ev[25];
    float mx = -1e30f;
    #pragma unroll
    for (int k = 0; k < 25; ++k) { ev[k] = ep[4*k]; mx = fmaxf(mx, ev[k]); }
    float sum = 0.f;
    #pragma unroll
    for (int k = 0; k < 25; ++k) { ev[k] = __expf(ev[k] - mx); sum += ev[k]; }
    const float rs = 1.f / sum;
    float* wp = Wl + px*112 + s*28;
    #pragma unroll
    for (int k = 0; k < 25; ++k) wp[k] = ev[k]*rs;
}

// ---------------------------------------------------------------------------
// Kernel C: reassembly (unchanged from R1).
// grid (cg=4 of 64 ch, h=48, b=2), block 256
// ---------------------------------------------------------------------------
__global__ __launch_bounds__(256) void carafe_kernel(
    const float* __restrict__ X, const float* __restrict__ Wl,
    float* __restrict__ out)
{
    const int cg = blockIdx.x;
    const int h = blockIdx.y;
    const int b = blockIdx.z;
    __shared__ float xl[16960];   // [(ci>>2)][r:5][cp:53][ci&3]
    __shared__ float wrow[5376];  // [w:48][s:4][28]
    const int tid = threadIdx.x;

    for (int idx = tid; idx < 64*265; idx += 256) {
        int ci  = idx / 265;
        int rem = idx - ci*265;
        int r   = rem / 53;
        int cp  = rem - r*53;
        int hh = h - 2 + r;
        int w  = cp - 2;
        float val = 0.f;
        if (hh >= 0 && hh < 48 && (unsigned)w < 48u)
            val = X[(b*256 + cg*64 + ci)*2304 + hh*48 + w];
        xl[(((ci>>2)*5 + r)*53 + cp)*4 + (ci&3)] = val;
    }
    for (int idx = tid; idx < 5376; idx += 256)
        wrow[idx] = Wl[((b*48 + h)*48)*112 + idx];
    __syncthreads();

    const int c4g = tid & 15;
    const int wg  = tid >> 4;
    for (int wi = 0; wi < 3; ++wi) {
        const int w = wg*3 + wi;
        float4 xv[25];
        #pragma unroll
        for (int r = 0; r < 5; ++r)
            #pragma unroll
            for (int dx = 0; dx < 5; ++dx)
                xv[r*5 + dx] = *(const float4*)&xl[((c4g*5 + r)*53 + (w + dx))*4];
        const float* wb = &wrow[w*112];
        #pragma unroll
        for (int s = 0; s < 4; ++s) {
            float ax=0.f, ay=0.f, az=0.f, aw=0.f;
            #pragma unroll
            for (int k4 = 0; k4 < 6; ++k4) {
                const float4 wv = *(const float4*)&wb[s*28 + k4*4];
                const float4 p0 = xv[k4*4+0], p1 = xv[k4*4+1], p2 = xv[k4*4+2], p3 = xv[k4*4+3];
                ax = fmaf(wv.x,p0.x,fmaf(wv.y,p1.x,fmaf(wv.z,p2.x,fmaf(wv.w,p3.x,ax))));
                ay = fmaf(wv.x,p0.y,fmaf(wv.y,p1.y,fmaf(wv.z,p2.y,fmaf(wv.w,p3.y,ay))));
                az = fmaf(wv.x,p0.z,fmaf(wv.y,p1.z,fmaf(wv.z,p2.z,fmaf(wv.w,p3.z,az))));
                aw = fmaf(wv.x,p0.w,fmaf(wv.y,p1.w,fmaf(wv.z,p2.w,fmaf(wv.w,p3.w,aw))));
            }
            const float wk = wb[s*28 + 24];
            const float4 pl = xv[24];
            ax = fmaf(wk,pl.x,ax); ay = fmaf(wk,pl.y,ay);
            az = fmaf(wk,pl.z,az); aw = fmaf(wk,pl.w,aw);
            const int y = 2*h + (s>>1);
            const int x = 2*w + (s&1);
            float* ob = &out[((size_t)(b*256 + cg*64 + c4g*4)*96 + y)*96 + x];
            ob[0]     = ax;
            ob[9216]  = ay;
            ob[18432] = az;
            ob[27648] = aw;
        }
    }
}

extern "C" void kernel_launch(void* const* d_in, const int* in_sizes, int n_in,
                              void* d_out, int out_size, void* d_ws, size_t ws_size,
                              hipStream_t stream)
{
    (void)in_sizes; (void)n_in; (void)out_size; (void)ws_size;
    const float* X      = (const float*)d_in[0];
    const float* w_comp = (const float*)d_in[1];
    const float* g1     = (const float*)d_in[2];
    const float* b1     = (const float*)d_in[3];
    const float* m1     = (const float*)d_in[4];
    const float* v1     = (const float*)d_in[5];
    const float* w_enc  = (const float*)d_in[6];
    const float* g2     = (const float*)d_in[7];
    const float* b2     = (const float*)d_in[8];
    const float* m2     = (const float*)d_in[9];
    const float* v2     = (const float*)d_in[10];
    float* out = (float*)d_out;

    char* ws = (char*)d_ws;
    unsigned short* tpad = (unsigned short*)(ws + 0);        // 2*50*50*64 bf16 = 640000 B
    unsigned short* Web  = (unsigned short*)(ws + 640000);   // 128*576 bf16    = 147456 B
    float*          e    = (float*)(ws + 787456);            // 4608*112 f32    = 2064384 B
    float*          Wl   = (float*)(ws + 2851840);           // 4608*112 f32    = 2064384 B

    prep_kernel<<<256, 256, 0, stream>>>(w_enc, (unsigned int*)tpad, Web);
    dim3 gA(2, 48, 2);
    comp_kernel<<<gA, 384, 0, stream>>>(X, w_comp, g1, b1, m1, v1, tpad);
    dim3 gB(3, 48, 2);
    enc_mfma<<<gB, 256, 0, stream>>>(tpad, Web, g2, b2, m2, v2, e);
    softmax_kernel<<<72, 256, 0, stream>>>(e, Wl);
    dim3 gC(4, 48, 2);
    carafe_kernel<<<gC, 256, 0, stream>>>(X, Wl, out);
}

// Round 3
// 62.082 us; speedup vs baseline: 2.3390x; 1.6039x over previous
//
#include <hip/hip_runtime.h>

#define EPS_BN 1e-5f

typedef __attribute__((ext_vector_type(8))) short short8v;
typedef __attribute__((ext_vector_type(4))) float f32x4;

__device__ inline unsigned short f2bf(float f) {
    union { float f; unsigned u; } v; v.f = f;
    unsigned r = v.u + 0x7fffu + ((v.u >> 16) & 1u);
    return (unsigned short)(r >> 16);
}

// ---------------------------------------------------------------------------
// Kernel P: zero t_pad, build Web[ch 128][kk*64+ci] bf16 from w_enc[ch][ci][kk]
// ---------------------------------------------------------------------------
__global__ __launch_bounds__(256) void prep_kernel(
    const float* __restrict__ w_enc, unsigned int* __restrict__ tpad_u32,
    unsigned short* __restrict__ Web)
{
    const int tid = blockIdx.x * 256 + threadIdx.x;
    const int nthr = gridDim.x * 256;
    for (int i = tid; i < 160000; i += nthr)       // 2*50*50*64 bf16 = 160000 u32
        tpad_u32[i] = 0u;
    for (int i = tid; i < 128 * 576; i += nthr) {
        int ch = i / 576;
        int r  = i - ch * 576;
        int kk = r >> 6;
        int ci = r & 63;
        float v = (ch < 100) ? w_enc[ch * 576 + ci * 9 + kk] : 0.f;
        Web[i] = f2bf(v);
    }
}

// ---------------------------------------------------------------------------
// Kernel A: 1x1 conv (256->64) + BN + SiLU -> t_pad bf16 [b][50][50][64]
// grid (ochalf=2, h=48, b=2), block 384
// ---------------------------------------------------------------------------
__global__ __launch_bounds__(384) void comp_kernel(
    const float* __restrict__ X, const float* __restrict__ Wc,
    const float* __restrict__ g1, const float* __restrict__ b1,
    const float* __restrict__ m1, const float* __restrict__ v1,
    unsigned short* __restrict__ tpad)
{
    const int ochalf = blockIdx.x;
    const int h = blockIdx.y;
    const int b = blockIdx.z;
    __shared__ float xrow[256*52];
    __shared__ float wc[32*260];
    const int tid = threadIdx.x;

    for (int idx = tid; idx < 256*48; idx += 384) {
        int ci = idx / 48;
        int w  = idx - ci*48;
        xrow[ci*52 + w] = X[(b*256 + ci)*2304 + h*48 + w];
    }
    for (int idx = tid; idx < 32*256; idx += 384) {
        int ocl = idx >> 8;
        int ci  = idx & 255;
        wc[ocl*260 + ci] = Wc[(ochalf*32 + ocl)*256 + ci];
    }
    __syncthreads();

    const int ocl = tid & 31;
    const int wg  = tid >> 5;
    const int w0  = wg*4;
    float a0=0.f, a1=0.f, a2=0.f, a3=0.f;
    for (int c4 = 0; c4 < 64; ++c4) {
        const float4 wv = *(const float4*)&wc[ocl*260 + c4*4];
        const float4 x0 = *(const float4*)&xrow[(c4*4+0)*52 + w0];
        const float4 x1 = *(const float4*)&xrow[(c4*4+1)*52 + w0];
        const float4 x2 = *(const float4*)&xrow[(c4*4+2)*52 + w0];
        const float4 x3 = *(const float4*)&xrow[(c4*4+3)*52 + w0];
        a0 = fmaf(wv.x,x0.x,fmaf(wv.y,x1.x,fmaf(wv.z,x2.x,fmaf(wv.w,x3.x,a0))));
        a1 = fmaf(wv.x,x0.y,fmaf(wv.y,x1.y,fmaf(wv.z,x2.y,fmaf(wv.w,x3.y,a1))));
        a2 = fmaf(wv.x,x0.z,fmaf(wv.y,x1.z,fmaf(wv.z,x2.z,fmaf(wv.w,x3.z,a2))));
        a3 = fmaf(wv.x,x0.w,fmaf(wv.y,x1.w,fmaf(wv.z,x2.w,fmaf(wv.w,x3.w,a3))));
    }
    const int oc = ochalf*32 + ocl;
    const float sc = g1[oc] * rsqrtf(v1[oc] + EPS_BN);
    const float sh = b1[oc] - m1[oc]*sc;
    float vals[4] = {a0, a1, a2, a3};
    #pragma unroll
    for (int wi = 0; wi < 4; ++wi) {
        float v = fmaf(vals[wi], sc, sh);
        float t = v / (1.f + __expf(-v));          // SiLU
        tpad[((b*50 + (h+1))*50 + (w0 + wi + 1))*64 + oc] = f2bf(t);
    }
}

// ---------------------------------------------------------------------------
// Kernel B1: 3x3 conv (64->100, padded to 112) via MFMA bf16, BN fused.
// e[px 4608][112] fp32.  grid (wseg=3, h=48, b=2), block 256 (4 waves).
// ---------------------------------------------------------------------------
__global__ __launch_bounds__(256) void enc_mfma(
    const unsigned short* __restrict__ tpad, const unsigned short* __restrict__ Web,
    const float* __restrict__ g2, const float* __restrict__ b2,
    const float* __restrict__ m2, const float* __restrict__ v2,
    float* __restrict__ e)
{
    const int wseg = blockIdx.x;
    const int h = blockIdx.y;
    const int b = blockIdx.z;
    const int tid  = threadIdx.x;
    const int wave = tid >> 6;
    const int l    = tid & 63;
    const int lr   = l & 15;
    const int lk   = l >> 4;
    const int w0   = wseg * 16;
    const int nt0  = wave * 2, nt1 = wave * 2 + 1;

    f32x4 acc0 = {0.f,0.f,0.f,0.f};
    f32x4 acc1 = {0.f,0.f,0.f,0.f};

    const unsigned short* tb = tpad + (b*50 + h)*50*64;
    const unsigned short* wb0 = Web + (nt0*16 + lr)*576;
    const unsigned short* wb1 = Web + (nt1*16 + lr)*576;

    #pragma unroll 6
    for (int s = 0; s < 18; ++s) {
        const int kk = s >> 1;
        const int ky = (kk * 11) >> 5;
        const int kx = kk - ky * 3;
        const int cio = ((s & 1) << 5) + lk * 8;
        const short8v a  = *(const short8v*)(tb + (ky*50 + w0 + kx + lr)*64 + cio);
        const short8v f0 = *(const short8v*)(wb0 + kk*64 + cio);
        const short8v f1 = *(const short8v*)(wb1 + kk*64 + cio);
        acc0 = __builtin_amdgcn_mfma_f32_16x16x32_bf16(a, f0, acc0, 0, 0, 0);
        acc1 = __builtin_amdgcn_mfma_f32_16x16x32_bf16(a, f1, acc1, 0, 0, 0);
    }

    float* erow = e + ((b*48 + h)*48 + w0 + lk*4)*112;
    #pragma unroll
    for (int t = 0; t < 2; ++t) {
        const int nt = t ? nt1 : nt0;
        if (nt >= 7) continue;
        const int ch = nt*16 + lr;
        float sc = 0.f, sh = 0.f;
        if (ch < 100) {
            sc = g2[ch] * rsqrtf(v2[ch] + EPS_BN);
            sh = b2[ch] - m2[ch]*sc;
        }
        const f32x4 acc = t ? acc1 : acc0;
        #pragma unroll
        for (int r = 0; r < 4; ++r)
            erow[r*112 + ch] = fmaf(acc[r], sc, sh);
    }
}

// ---------------------------------------------------------------------------
// Kernel B2: per-(px,s) softmax over k=0..24.  e[px][4k+s] -> Wl[px][s*28+k]
// ---------------------------------------------------------------------------
__global__ __launch_bounds__(256) void softmax_kernel(
    const float* __restrict__ e, float* __restrict__ Wl)
{
    const int g = blockIdx.x * 256 + threadIdx.x;
    const int px = g >> 2;
    const int s  = g & 3;
    const float* ep = e + px*112 + s;
    float ev[25];
    float mx = -1e30f;
    #pragma unroll
    for (int k = 0; k < 25; ++k) { ev[k] = ep[4*k]; mx = fmaxf(mx, ev[k]); }
    float sum = 0.f;
    #pragma unroll
    for (int k = 0; k < 25; ++k) { ev[k] = __expf(ev[k] - mx); sum += ev[k]; }
    const float rs = 1.f / sum;
    float* wp = Wl + px*112 + s*28;
    #pragma unroll
    for (int k = 0; k < 25; ++k) wp[k] = ev[k]*rs;
}

// ---------------------------------------------------------------------------
// Kernel C v3: reassembly, 16 channels/block, small LDS (39 KB), 1536 blocks.
// grid (cg=16, h=48, b=2), block 256.  c4g = tid&3 (4 ch), w = tid>>2 (48 act)
// ---------------------------------------------------------------------------
__global__ __launch_bounds__(256) void carafe_kernel(
    const float* __restrict__ X, const float* __restrict__ Wl,
    float* __restrict__ out)
{
    const int cg = blockIdx.x;
    const int h = blockIdx.y;
    const int b = blockIdx.z;
    __shared__ float xl[4240];    // [(ci>>2):4][r:5][cp:53][ci&3]
    __shared__ float wrow[5568];  // [w:48][116], 112 used (stride 116: bank-spread)
    const int tid = threadIdx.x;

    for (int idx = tid; idx < 16*265; idx += 256) {
        int ci  = idx / 265;
        int rem = idx - ci*265;
        int r   = rem / 53;
        int cp  = rem - r*53;
        int hh = h - 2 + r;
        int w  = cp - 2;
        float val = 0.f;
        if (hh >= 0 && hh < 48 && (unsigned)w < 48u)
            val = X[(b*256 + cg*16 + ci)*2304 + hh*48 + w];
        xl[(((ci>>2)*5 + r)*53 + cp)*4 + (ci&3)] = val;
    }
    {
        const float* wsrc = &Wl[((b*48 + h)*48)*112];
        for (int idx = tid; idx < 5376; idx += 256) {
            int w = idx / 112;
            int j = idx - w*112;
            wrow[w*116 + j] = wsrc[idx];
        }
    }
    __syncthreads();

    const int c4g = tid & 3;     // channel quad: cg*16 + c4g*4 + {0..3}
    const int w   = tid >> 2;    // 0..63, active < 48
    if (w < 48) {
        float4 xv[25];
        #pragma unroll
        for (int r = 0; r < 5; ++r)
            #pragma unroll
            for (int dx = 0; dx < 5; ++dx)
                xv[r*5 + dx] = *(const float4*)&xl[((c4g*5 + r)*53 + (w + dx))*4];
        const float* wb = &wrow[w*116];
        #pragma unroll
        for (int s = 0; s < 4; ++s) {
            float ax=0.f, ay=0.f, az=0.f, aw=0.f;
            #pragma unroll
            for (int k4 = 0; k4 < 6; ++k4) {
                const float4 wv = *(const float4*)&wb[s*28 + k4*4];
                const float4 p0 = xv[k4*4+0], p1 = xv[k4*4+1], p2 = xv[k4*4+2], p3 = xv[k4*4+3];
                ax = fmaf(wv.x,p0.x,fmaf(wv.y,p1.x,fmaf(wv.z,p2.x,fmaf(wv.w,p3.x,ax))));
                ay = fmaf(wv.x,p0.y,fmaf(wv.y,p1.y,fmaf(wv.z,p2.y,fmaf(wv.w,p3.y,ay))));
                az = fmaf(wv.x,p0.z,fmaf(wv.y,p1.z,fmaf(wv.z,p2.z,fmaf(wv.w,p3.z,az))));
                aw = fmaf(wv.x,p0.w,fmaf(wv.y,p1.w,fmaf(wv.z,p2.w,fmaf(wv.w,p3.w,aw))));
            }
            const float wk = wb[s*28 + 24];
            const float4 pl = xv[24];
            ax = fmaf(wk,pl.x,ax); ay = fmaf(wk,pl.y,ay);
            az = fmaf(wk,pl.z,az); aw = fmaf(wk,pl.w,aw);
            const int y = 2*h + (s>>1);
            const int x = 2*w + (s&1);
            float* ob = &out[((size_t)(b*256 + cg*16 + c4g*4)*96 + y)*96 + x];
            ob[0]     = ax;
            ob[9216]  = ay;
            ob[18432] = az;
            ob[27648] = aw;
        }
    }
}

extern "C" void kernel_launch(void* const* d_in, const int* in_sizes, int n_in,
                              void* d_out, int out_size, void* d_ws, size_t ws_size,
                              hipStream_t stream)
{
    (void)in_sizes; (void)n_in; (void)out_size; (void)ws_size;
    const float* X      = (const float*)d_in[0];
    const float* w_comp = (const float*)d_in[1];
    const float* g1     = (const float*)d_in[2];
    const float* b1     = (const float*)d_in[3];
    const float* m1     = (const float*)d_in[4];
    const float* v1     = (const float*)d_in[5];
    const float* w_enc  = (const float*)d_in[6];
    const float* g2     = (const float*)d_in[7];
    const float* b2     = (const float*)d_in[8];
    const float* m2     = (const float*)d_in[9];
    const float* v2     = (const float*)d_in[10];
    float* out = (float*)d_out;

    char* ws = (char*)d_ws;
    unsigned short* tpad = (unsigned short*)(ws + 0);        // 2*50*50*64 bf16 = 640000 B
    unsigned short* Web  = (unsigned short*)(ws + 640000);   // 128*576 bf16    = 147456 B
    float*          e    = (float*)(ws + 787456);            // 4608*112 f32    = 2064384 B
    float*          Wl   = (float*)(ws + 2851840);           // 4608*112 f32    = 2064384 B

    prep_kernel<<<256, 256, 0, stream>>>(w_enc, (unsigned int*)tpad, Web);
    dim3 gA(2, 48, 2);
    comp_kernel<<<gA, 384, 0, stream>>>(X, w_comp, g1, b1, m1, v1, tpad);
    dim3 gB(3, 48, 2);
    enc_mfma<<<gB, 256, 0, stream>>>(tpad, Web, g2, b2, m2, v2, e);
    softmax_kernel<<<72, 256, 0, stream>>>(e, Wl);
    dim3 gC(16, 48, 2);
    carafe_kernel<<<gC, 256, 0, stream>>>(X, Wl, out);
}

// Round 4
// 53.614 us; speedup vs baseline: 2.7084x; 1.1579x over previous
//
#include <hip/hip_runtime.h>

#define EPS_BN 1e-5f

typedef __attribute__((ext_vector_type(8))) short short8v;
typedef __attribute__((ext_vector_type(4))) float f32x4;

__device__ inline unsigned short f2bf(float f) {
    union { float f; unsigned u; } v; v.f = f;
    unsigned r = v.u + 0x7fffu + ((v.u >> 16) & 1u);
    return (unsigned short)(r >> 16);
}

// ---------------------------------------------------------------------------
// Kernel P: zero t_pad (uint4), build Web[ch128][kk*64+ci] bf16, Wcb[oc][ci] bf16
// ---------------------------------------------------------------------------
__global__ __launch_bounds__(256) void prep_kernel(
    const float* __restrict__ w_enc, const float* __restrict__ w_comp,
    uint4* __restrict__ tpad_v, unsigned short* __restrict__ Web,
    unsigned short* __restrict__ Wcb)
{
    const int tid = blockIdx.x * 256 + threadIdx.x;
    const int nthr = gridDim.x * 256;
    const uint4 z = {0u,0u,0u,0u};
    for (int i = tid; i < 40000; i += nthr)        // 2*50*50*64 bf16 = 40000 uint4
        tpad_v[i] = z;
    for (int i = tid; i < 128 * 576; i += nthr) {
        int ch = i / 576;
        int r  = i - ch * 576;
        int kk = r >> 6;
        int ci = r & 63;
        float v = (ch < 100) ? w_enc[ch * 576 + ci * 9 + kk] : 0.f;
        Web[i] = f2bf(v);
    }
    for (int i = tid; i < 64 * 256; i += nthr)
        Wcb[i] = f2bf(w_comp[i]);
}

// ---------------------------------------------------------------------------
// Kernel A v2: 1x1 conv (256->64) via MFMA bf16 + BN + SiLU -> tpad bf16.
// M=4608 px (16/block), K=256 (8 steps), N=64 (4 waves x 1 n-tile).
// Zero LDS, no barriers.  grid (wseg=3, h=48, b=2), block 256.
// ---------------------------------------------------------------------------
__global__ __launch_bounds__(256) void comp_mfma(
    const float* __restrict__ X, const unsigned short* __restrict__ Wcb,
    const float* __restrict__ g1, const float* __restrict__ b1,
    const float* __restrict__ m1, const float* __restrict__ v1,
    unsigned short* __restrict__ tpad)
{
    const int wseg = blockIdx.x;
    const int h = blockIdx.y;
    const int b = blockIdx.z;
    const int tid  = threadIdx.x;
    const int wave = tid >> 6;
    const int l    = tid & 63;
    const int lr   = l & 15;      // A-row (px) / B-col (oc) in tile
    const int lk   = l >> 4;      // k-group
    const int w0   = wseg * 16;

    f32x4 acc = {0.f,0.f,0.f,0.f};
    const float* xb = X + (size_t)b * 589824 + h * 48 + w0 + lr;   // + ci*2304
    const unsigned short* wb = Wcb + (wave * 16 + lr) * 256;

    #pragma unroll
    for (int s = 0; s < 8; ++s) {
        const int ci0 = s * 32 + lk * 8;
        short8v a;
        #pragma unroll
        for (int j = 0; j < 8; ++j)
            a[j] = (short)f2bf(xb[(size_t)(ci0 + j) * 2304]);
        const short8v f = *(const short8v*)(wb + ci0);
        acc = __builtin_amdgcn_mfma_f32_16x16x32_bf16(a, f, acc, 0, 0, 0);
    }

    const int oc = wave * 16 + lr;
    const float sc = g1[oc] * rsqrtf(v1[oc] + EPS_BN);
    const float sh = b1[oc] - m1[oc] * sc;
    unsigned short* tp = tpad + ((b*50 + h + 1)*50 + 1)*64 + oc;
    #pragma unroll
    for (int r = 0; r < 4; ++r) {
        float v = fmaf(acc[r], sc, sh);
        float t = v / (1.f + __expf(-v));          // SiLU
        tp[(w0 + lk*4 + r)*64] = f2bf(t);
    }
}

// ---------------------------------------------------------------------------
// Kernel B v2: 3x3 conv (64->100) MFMA + BN + fused per-(px,s) softmax -> Wl.
// grid (wseg=3, h=48, b=2), block 256 (4 waves).  elds 7.4 KB.
// ---------------------------------------------------------------------------
__global__ __launch_bounds__(256) void enc_sm(
    const unsigned short* __restrict__ tpad, const unsigned short* __restrict__ Web,
    const float* __restrict__ g2, const float* __restrict__ b2,
    const float* __restrict__ m2, const float* __restrict__ v2,
    float* __restrict__ Wl)
{
    const int wseg = blockIdx.x;
    const int h = blockIdx.y;
    const int b = blockIdx.z;
    const int tid  = threadIdx.x;
    const int wave = tid >> 6;
    const int l    = tid & 63;
    const int lr   = l & 15;
    const int lk   = l >> 4;
    const int w0   = wseg * 16;
    const int nt0  = wave * 2, nt1 = wave * 2 + 1;
    __shared__ float elds[16 * 116];

    f32x4 acc0 = {0.f,0.f,0.f,0.f};
    f32x4 acc1 = {0.f,0.f,0.f,0.f};

    const unsigned short* tb = tpad + (b*50 + h)*50*64;
    const unsigned short* wb0 = Web + (nt0*16 + lr)*576;
    const unsigned short* wb1 = Web + (nt1*16 + lr)*576;

    #pragma unroll 6
    for (int s = 0; s < 18; ++s) {
        const int kk = s >> 1;
        const int ky = (kk * 11) >> 5;
        const int kx = kk - ky * 3;
        const int cio = ((s & 1) << 5) + lk * 8;
        const short8v a  = *(const short8v*)(tb + (ky*50 + w0 + kx + lr)*64 + cio);
        const short8v f0 = *(const short8v*)(wb0 + kk*64 + cio);
        const short8v f1 = *(const short8v*)(wb1 + kk*64 + cio);
        acc0 = __builtin_amdgcn_mfma_f32_16x16x32_bf16(a, f0, acc0, 0, 0, 0);
        acc1 = __builtin_amdgcn_mfma_f32_16x16x32_bf16(a, f1, acc1, 0, 0, 0);
    }

    #pragma unroll
    for (int t = 0; t < 2; ++t) {
        const int nt = t ? nt1 : nt0;
        if (nt >= 7) continue;
        const int ch = nt*16 + lr;
        float sc = 0.f, sh = 0.f;
        if (ch < 100) {
            sc = g2[ch] * rsqrtf(v2[ch] + EPS_BN);
            sh = b2[ch] - m2[ch]*sc;
        }
        const f32x4 acc = t ? acc1 : acc0;
        #pragma unroll
        for (int r = 0; r < 4; ++r)
            elds[(lk*4 + r)*116 + ch] = fmaf(acc[r], sc, sh);
    }
    __syncthreads();

    if (tid < 64) {
        const int px = tid >> 2;
        const int s  = tid & 3;
        const float* ep = &elds[px*116 + s];
        float ev[25];
        float mx = -1e30f;
        #pragma unroll
        for (int k = 0; k < 25; ++k) { ev[k] = ep[4*k]; mx = fmaxf(mx, ev[k]); }
        float sum = 0.f;
        #pragma unroll
        for (int k = 0; k < 25; ++k) { ev[k] = __expf(ev[k] - mx); sum += ev[k]; }
        const float rs = 1.f / sum;
        float* wp = Wl + ((b*48 + h)*48 + w0 + px)*112 + s*28;
        #pragma unroll
        for (int k4 = 0; k4 < 6; ++k4) {
            float4 o = { ev[k4*4+0]*rs, ev[k4*4+1]*rs, ev[k4*4+2]*rs, ev[k4*4+3]*rs };
            *(float4*)(wp + k4*4) = o;
        }
        wp[24] = ev[24]*rs;
    }
}

// ---------------------------------------------------------------------------
// Kernel C v3: reassembly, 16 channels/block, 39 KB LDS, 1536 blocks.
// ---------------------------------------------------------------------------
__global__ __launch_bounds__(256) void carafe_kernel(
    const float* __restrict__ X, const float* __restrict__ Wl,
    float* __restrict__ out)
{
    const int cg = blockIdx.x;
    const int h = blockIdx.y;
    const int b = blockIdx.z;
    __shared__ float xl[4240];    // [(ci>>2):4][r:5][cp:53][ci&3]
    __shared__ float wrow[5568];  // [w:48][116]
    const int tid = threadIdx.x;

    for (int idx = tid; idx < 16*265; idx += 256) {
        int ci  = idx / 265;
        int rem = idx - ci*265;
        int r   = rem / 53;
        int cp  = rem - r*53;
        int hh = h - 2 + r;
        int w  = cp - 2;
        float val = 0.f;
        if (hh >= 0 && hh < 48 && (unsigned)w < 48u)
            val = X[(b*256 + cg*16 + ci)*2304 + hh*48 + w];
        xl[(((ci>>2)*5 + r)*53 + cp)*4 + (ci&3)] = val;
    }
    {
        const float* wsrc = &Wl[((b*48 + h)*48)*112];
        for (int idx = tid; idx < 5376; idx += 256) {
            int w = idx / 112;
            int j = idx - w*112;
            wrow[w*116 + j] = wsrc[idx];
        }
    }
    __syncthreads();

    const int c4g = tid & 3;
    const int w   = tid >> 2;
    if (w < 48) {
        float4 xv[25];
        #pragma unroll
        for (int r = 0; r < 5; ++r)
            #pragma unroll
            for (int dx = 0; dx < 5; ++dx)
                xv[r*5 + dx] = *(const float4*)&xl[((c4g*5 + r)*53 + (w + dx))*4];
        const float* wb = &wrow[w*116];
        #pragma unroll
        for (int s = 0; s < 4; ++s) {
            float ax=0.f, ay=0.f, az=0.f, aw=0.f;
            #pragma unroll
            for (int k4 = 0; k4 < 6; ++k4) {
                const float4 wv = *(const float4*)&wb[s*28 + k4*4];
                const float4 p0 = xv[k4*4+0], p1 = xv[k4*4+1], p2 = xv[k4*4+2], p3 = xv[k4*4+3];
                ax = fmaf(wv.x,p0.x,fmaf(wv.y,p1.x,fmaf(wv.z,p2.x,fmaf(wv.w,p3.x,ax))));
                ay = fmaf(wv.x,p0.y,fmaf(wv.y,p1.y,fmaf(wv.z,p2.y,fmaf(wv.w,p3.y,ay))));
                az = fmaf(wv.x,p0.z,fmaf(wv.y,p1.z,fmaf(wv.z,p2.z,fmaf(wv.w,p3.z,az))));
                aw = fmaf(wv.x,p0.w,fmaf(wv.y,p1.w,fmaf(wv.z,p2.w,fmaf(wv.w,p3.w,aw))));
            }
            const float wk = wb[s*28 + 24];
            const float4 pl = xv[24];
            ax = fmaf(wk,pl.x,ax); ay = fmaf(wk,pl.y,ay);
            az = fmaf(wk,pl.z,az); aw = fmaf(wk,pl.w,aw);
            const int y = 2*h + (s>>1);
            const int x = 2*w + (s&1);
            float* ob = &out[((size_t)(b*256 + cg*16 + c4g*4)*96 + y)*96 + x];
            ob[0]     = ax;
            ob[9216]  = ay;
            ob[18432] = az;
            ob[27648] = aw;
        }
    }
}

extern "C" void kernel_launch(void* const* d_in, const int* in_sizes, int n_in,
                              void* d_out, int out_size, void* d_ws, size_t ws_size,
                              hipStream_t stream)
{
    (void)in_sizes; (void)n_in; (void)out_size; (void)ws_size;
    const float* X      = (const float*)d_in[0];
    const float* w_comp = (const float*)d_in[1];
    const float* g1     = (const float*)d_in[2];
    const float* b1     = (const float*)d_in[3];
    const float* m1     = (const float*)d_in[4];
    const float* v1     = (const float*)d_in[5];
    const float* w_enc  = (const float*)d_in[6];
    const float* g2     = (const float*)d_in[7];
    const float* b2     = (const float*)d_in[8];
    const float* m2     = (const float*)d_in[9];
    const float* v2     = (const float*)d_in[10];
    float* out = (float*)d_out;

    char* ws = (char*)d_ws;
    unsigned short* tpad = (unsigned short*)(ws + 0);        // 640000 B
    unsigned short* Web  = (unsigned short*)(ws + 640000);   // 147456 B
    unsigned short* Wcb  = (unsigned short*)(ws + 787456);   // 32768 B
    float*          Wl   = (float*)(ws + 820224);            // 2064384 B

    prep_kernel<<<128, 256, 0, stream>>>(w_enc, w_comp, (uint4*)tpad, Web, Wcb);
    dim3 gA(3, 48, 2);
    comp_mfma<<<gA, 256, 0, stream>>>(X, Wcb, g1, b1, m1, v1, tpad);
    dim3 gB(3, 48, 2);
    enc_sm<<<gB, 256, 0, stream>>>(tpad, Web, g2, b2, m2, v2, Wl);
    dim3 gC(16, 48, 2);
    carafe_kernel<<<gC, 256, 0, stream>>>(X, Wl, out);
}